// Round 9
// baseline (253.793 us; speedup 1.0000x reference)
//
#include <hip/hip_runtime.h>

typedef unsigned short ushort_t;
typedef unsigned int uint_t;
typedef __bf16 bf16x8 __attribute__((ext_vector_type(8)));
typedef float f32x4 __attribute__((ext_vector_type(4)));

#define BM 128
#define BN 128

static constexpr float LRC  = 0.3f;
static constexpr float AC   = (float)(0.3 * 1e-4);          // LR*DSBETA
static constexpr float OMAC = (float)(1.0 - 0.3 * 1e-4);    // 1 - LR*DSBETA
static constexpr float EPSC = 0.01f;                        // EPS_DS
static constexpr float ATC  = 0.9f;                         // AT
static constexpr float DELTA = 5e-4f;   // screen margin, ~33 sigma of hh act err

__device__ __forceinline__ void gll16(const void* g, void* l) {
    __builtin_amdgcn_global_load_lds((__attribute__((address_space(1))) void*)g,
                                     (__attribute__((address_space(3))) void*)l,
                                     16, 0, 0);
}

__device__ __forceinline__ ushort_t f2bf_rne(float f) {
    uint_t u = __float_as_uint(f);
    uint_t r = u + 0x7fffu + ((u >> 16) & 1u);
    return (ushort_t)(r >> 16);
}

// -------- kernel A: prep: X/W -> hi bf16 plane + row stats + zero counters ---
__global__ __launch_bounds__(128) void k_prep(
    const float* __restrict__ X, const float* __restrict__ W,
    const float* __restrict__ REL,
    ushort_t* __restrict__ Xh, ushort_t* __restrict__ Wh,
    float* __restrict__ xsq, float* __restrict__ wsq, float* __restrict__ rel_sum,
    int* __restrict__ cnt, int* __restrict__ cnt_l, float* __restrict__ outLoss,
    int B, int D)
{
    int blk = blockIdx.x, t = threadIdx.x;
    bool isX = blk < B;
    int row = isX ? blk : blk - B;
    if (blk == 0 && t == 0) *outLoss = 0.f;
    if (!isX && t == 0) { cnt[row] = 0; cnt_l[row] = 0; }
    const float4* src = (const float4*)((isX ? X : W) + (size_t)row * D);
    const float4* rr  = isX ? nullptr : (const float4*)(REL + (size_t)row * D);
    ushort_t* H = isX ? Xh : Wh;
    float q = 0.f, r = 0.f;
    for (int i = t; i < (D >> 2); i += 128) {
        float4 v = src[i];
        if (!isX) { float4 rv = rr[i]; r += rv.x + rv.y + rv.z + rv.w; }
        float x[4] = {v.x, v.y, v.z, v.w};
        ushort_t h[4];
#pragma unroll
        for (int j = 0; j < 4; j++) { q += x[j] * x[j]; h[j] = f2bf_rne(x[j]); }
        ((ushort4*)H)[(size_t)row * (D >> 2) + i] = make_ushort4(h[0], h[1], h[2], h[3]);
    }
    __shared__ float s1[128], s2[128];
    s1[t] = q; s2[t] = r; __syncthreads();
    for (int off = 64; off > 0; off >>= 1) {
        if (t < off) { s1[t] += s1[t + off]; s2[t] += s2[t + off]; }
        __syncthreads();
    }
    if (t == 0) {
        if (isX) xsq[row] = s1[0];
        else { wsq[row] = s1[0]; rel_sum[row] = s2[0]; }
    }
}

// --- kernel B: 1-pass hh bf16 MFMA screen GEMM, division-free q-space epilogue
__global__ __launch_bounds__(256, 2) void k_gemm_act(
    const ushort_t* __restrict__ Xh, const ushort_t* __restrict__ Wh,
    const float* __restrict__ xsq, const float* __restrict__ wsq,
    const float* __restrict__ rs,
    float* __restrict__ tmaxA, int* __restrict__ cntA,
    float* __restrict__ actsA, int* __restrict__ idxsA,
    int K, int D)
{
    __shared__ char smem[26624];

    const int tid = threadIdx.x;
    const int wave = tid >> 6, lane = tid & 63;
    const int nk = K / BN;
    const int bx = blockIdx.x % nk, by = blockIdx.x / nk;
    const int b0 = by * BM, k0 = bx * BN;

    const int srow = wave * 32 + (lane >> 2);
    const int schunk = ((lane & 3) - (lane >> 3)) & 3;
    const int scol = schunk * 8;
    const size_t gx = (size_t)(b0 + srow) * D + scol;
    const size_t gw = (size_t)(k0 + srow) * D + scol;
    const size_t c1 = (size_t)16 * D;
    char* lb = smem + wave * 2048;

    const int wm = wave >> 1, wn = wave & 1;
    const int l15 = lane & 15, quad = lane >> 4;
    const int roff = (l15 * 4 + ((quad + (l15 >> 1)) & 3)) * 16;
    const int aoff = (wm * 4) * 1024 + roff;
    const int boff = (wn * 4) * 1024 + roff;

    f32x4 acc[4][4];
#pragma unroll
    for (int i = 0; i < 4; i++)
#pragma unroll
        for (int j = 0; j < 4; j++) acc[i][j] = (f32x4){0.f, 0.f, 0.f, 0.f};

    for (int kd = 0; kd < D; kd += 32) {
        gll16(Xh + gx + kd,      lb + 0);
        gll16(Xh + gx + c1 + kd, lb + 1024);
        gll16(Wh + gw + kd,      lb + 8192);
        gll16(Wh + gw + c1 + kd, lb + 8192 + 1024);
        __syncthreads();

        bf16x8 ah[4], bh[4];
#pragma unroll
        for (int t = 0; t < 4; t++) {
            ah[t] = *(const bf16x8*)(smem + 0    + aoff + t * 1024);
            bh[t] = *(const bf16x8*)(smem + 8192 + boff + t * 1024);
        }
#pragma unroll
        for (int j = 0; j < 4; j++)
#pragma unroll
            for (int i = 0; i < 4; i++)
                acc[i][j] = __builtin_amdgcn_mfma_f32_16x16x32_bf16(ah[i], bh[j], acc[i][j], 0, 0, 0);
        __syncthreads();
    }

    float rsv[4], wqv[4], epsors[4];
#pragma unroll
    for (int tn = 0; tn < 4; tn++) {
        int c = k0 + wn * 64 + tn * 16 + l15;
        float rv = rs[c];
        rsv[tn] = rv; wqv[tn] = wsq[c];
        epsors[tn] = 1e-7f / rv;
    }
    const float invD = 1.f / (float)D;
    float* redM    = (float*)smem;              // [128][33]  qmin
    float* tmaxrow = (float*)(smem + 16896);
    float* thrqrow = (float*)(smem + 17408);
    int*   cntL    = (int*)(smem + 17920);
    float* lsActs  = (float*)(smem + 18432);
    int*   lsIdx   = (int*)(smem + 22528);

#pragma unroll
    for (int tm = 0; tm < 4; tm++) {
#pragma unroll
        for (int r = 0; r < 4; r++) {
            int rowl = wm * 64 + tm * 16 + quad * 4 + r;
            float xq = xsq[b0 + rowl];
            float qmin = 1e30f;
#pragma unroll
            for (int tn = 0; tn < 4; tn++) {
                float dd = (xq + wqv[tn]) - 2.f * acc[tm][tn][r];
                float q = dd * invD + epsors[tn];
                acc[tm][tn][r] = q;
                qmin = fminf(qmin, q);
            }
            redM[rowl * 33 + wn * 16 + l15] = qmin;
        }
    }
    __syncthreads();
    if (tid < BM) {
        float qm = 1e30f;
#pragma unroll
        for (int t2 = 0; t2 < 32; t2++) qm = fminf(qm, redM[tid * 33 + t2]);
        float tmax = 1.f / (1.f + qm);
        tmaxrow[tid] = tmax;
        thrqrow[tid] = 1.f / (tmax - DELTA) - 1.f;
        cntL[tid] = 0;
    }
    __syncthreads();
#pragma unroll
    for (int tm = 0; tm < 4; tm++) {
#pragma unroll
        for (int r = 0; r < 4; r++) {
            int rowl = wm * 64 + tm * 16 + quad * 4 + r;
            float tq = thrqrow[rowl];
#pragma unroll
            for (int tn = 0; tn < 4; tn++) {
                float q = acc[tm][tn][r];
                if (q <= tq) {
                    int pos = atomicAdd(&cntL[rowl], 1);
                    if (pos < 8) {
                        lsActs[rowl * 8 + pos] = 1.f / (1.f + q);
                        lsIdx[rowl * 8 + pos]  = k0 + wn * 64 + tn * 16 + l15;
                    }
                }
            }
        }
    }
    __syncthreads();
    if (tid < BM) {
        size_t base = (size_t)(b0 + tid) * nk + bx;
        tmaxA[base] = tmaxrow[tid];
        int c = cntL[tid];
        cntA[base] = c;
        int cc = c < 8 ? c : 8;
        for (int s = 0; s < cc; s++) {
            actsA[base * 8 + s] = lsActs[tid * 8 + s];
            idxsA[base * 8 + s] = lsIdx[tid * 8 + s];
        }
    }
}

// ---- kernel C: exact fp32 refine of candidates + BMU + rank -----------------
__global__ __launch_bounds__(64) void k_refine(
    const float* __restrict__ X, const float* __restrict__ W,
    const float* __restrict__ xsq, const float* __restrict__ wsq,
    const float* __restrict__ rs,
    const float* __restrict__ tmaxA, const int* __restrict__ cntA,
    const float* __restrict__ actsA, const int* __restrict__ idxsA,
    int nk, int* __restrict__ cnt, int* __restrict__ cnt_l,
    int* __restrict__ idxb, int* __restrict__ rankb, int* __restrict__ highb,
    int K, int D)
{
    int b = blockIdx.x, ln = threadIdx.x;
    const float4* xp = (const float4*)(X + (size_t)b * D + ln * 8);
    float4 xa = xp[0], xb = xp[1];
    float xr[8] = {xa.x, xa.y, xa.z, xa.w, xb.x, xb.y, xb.z, xb.w};
    float xq = xsq[b];
    const float invD = 1.f / (float)D;

    float tmax = (ln < nk) ? tmaxA[(size_t)b * nk + ln] : -1e30f;
    int   tcnt = (ln < nk) ? cntA[(size_t)b * nk + ln] : 0;
    float M = tmax;
#pragma unroll
    for (int o = 32; o > 0; o >>= 1) M = fmaxf(M, __shfl_xor(M, o));
    float thr = M - DELTA;

    float best = -1e30f; int bidx = 0x7fffffff;

    auto exact_upd = [&](int idx) {
        const float* wr = W + (size_t)idx * D + ln * 8;
        float p = 0.f;
#pragma unroll
        for (int j = 0; j < 8; j++) p = fmaf(xr[j], wr[j], p);
#pragma unroll
        for (int o = 32; o > 0; o >>= 1) p += __shfl_xor(p, o);
        float rsv = rs[idx];
        float dd = (xq + wsq[idx]) - 2.f * p;
        float dw = dd * (rsv * invD);
        if (dw != dw) dw = 0.f;
        float act = rsv / ((rsv + dw) + 1e-7f);
        if (act > best || (act == best && idx < bidx)) { best = act; bidx = idx; }
    };

    for (int t = 0; t < nk; t++) {
        float tm = __shfl(tmax, t);
        int   tc = __shfl(tcnt, t);
        if (tm < thr) continue;
        if (tc <= 8) {
            size_t base = ((size_t)b * nk + t) * 8;
            for (int s = 0; s < tc; s++) {
                float aact = actsA[base + s];
                if (aact < thr) continue;
                exact_upd(idxsA[base + s]);
            }
        } else {
            for (int k2 = t * BN; k2 < t * BN + BN; k2++) exact_upd(k2);
        }
    }

    if (ln == 0) {
        int hi = (best >= ATC) ? 1 : 0;
        int rank = atomicAdd((hi ? cnt : cnt_l) + bidx, 1);
        idxb[b] = bidx; rankb[b] = rank; highb[b] = hi;
    }
}

// ---- kernel D: offsets + slot_src map (one block, shuffle scans) ------------
__global__ __launch_bounds__(1024) void k_offsets(
    const int* __restrict__ cnt, const int* __restrict__ cnt_l,
    const float* __restrict__ NC,
    int* __restrict__ offs_h, int* __restrict__ offs_l,
    int* __restrict__ slot_src, int K)
{
    __shared__ int wsumA[16], wsumB[16];
    __shared__ int lowL[4096], availL[4096];
    int t = threadIdx.x, ln = t & 63, wv = t >> 6;
    int per = (K + 1023) / 1024;     // 4
    int base = t * per;

    // ---- pass 1: exclusive offsets for high and low lists ----
    int ch[8], cl[8]; int sh = 0, sl = 0;
    for (int j = 0; j < per; j++) {
        int k = base + j;
        int a = (k < K) ? cnt[k] : 0;
        int b = (k < K) ? cnt_l[k] : 0;
        ch[j] = a; cl[j] = b; sh += a; sl += b;
    }
    int ia = sh, ib = sl;               // inclusive wave scan
#pragma unroll
    for (int o = 1; o < 64; o <<= 1) {
        int ua = __shfl_up(ia, o), ub = __shfl_up(ib, o);
        if (ln >= o) { ia += ua; ib += ub; }
    }
    if (ln == 63) { wsumA[wv] = ia; wsumB[wv] = ib; }
    __syncthreads();
    int woA = 0, woB = 0;
    for (int i = 0; i < wv; i++) { woA += wsumA[i]; woB += wsumB[i]; }
    int eh = woA + ia - sh, el = woB + ib - sl;
    for (int j = 0; j < per; j++) {
        int k = base + j;
        if (k < K) { offs_h[k] = eh; offs_l[k] = el; }
        eh += ch[j]; el += cl[j];
    }
    __syncthreads();

    // ---- pass 2: low_valid / avail compaction into LDS ----
    int lv[8], av[8]; int cL = 0, cA = 0;
    for (int j = 0; j < per; j++) {
        int k = base + j;
        int l = 0, a = 0;
        if (k < K) {
            l = (cl[j] > 0) ? 1 : 0;
            float nc1 = (ch[j] > 0) ? 1.f : NC[k];
            a = (nc1 == 0.f) ? 1 : 0;
        }
        lv[j] = l; av[j] = a; cL += l; cA += a;
    }
    ia = cL; ib = cA;
#pragma unroll
    for (int o = 1; o < 64; o <<= 1) {
        int ua = __shfl_up(ia, o), ub = __shfl_up(ib, o);
        if (ln >= o) { ia += ua; ib += ub; }
    }
    if (ln == 63) { wsumA[wv] = ia; wsumB[wv] = ib; }
    __syncthreads();
    woA = 0; woB = 0;
    int totL = 0, totA = 0;
    for (int i = 0; i < 16; i++) {
        if (i < wv) { woA += wsumA[i]; woB += wsumB[i]; }
        totL += wsumA[i]; totA += wsumB[i];
    }
    int eL = woA + ia - cL, eA = woB + ib - cA;
    for (int j = 0; j < per; j++) {
        if (lv[j]) lowL[eL++] = base + j;
        if (av[j]) availL[eA++] = base + j;
    }
    for (int j = 0; j < per; j++) {
        int k = base + j;
        if (k < K) slot_src[k] = -1;
    }
    __syncthreads();
    int n_create = (totL < totA) ? totL : totA;
    for (int r = t; r < n_create; r += 1024)
        slot_src[availL[r]] = lowL[totL - n_create + r];
}

// ---- kernel E: scatter sample ids into per-node lists -----------------------
__global__ __launch_bounds__(256) void k_scatter(
    const int* __restrict__ idxb, const int* __restrict__ rankb,
    const int* __restrict__ highb,
    const int* __restrict__ offs_h, const int* __restrict__ offs_l,
    int* __restrict__ list_h, int* __restrict__ list_l, int B)
{
    int b = blockIdx.x * 256 + threadIdx.x;
    if (b >= B) return;
    int node = idxb[b];
    if (highb[b]) list_h[offs_h[node] + rankb[b]] = b;
    else          list_l[offs_l[node] + rankb[b]] = b;
}

// ---- kernel F: fused per-node output — ONE WAVE PER NODE, no barriers -------
__global__ __launch_bounds__(256) void k_final(
    const float* __restrict__ X,
    const float* __restrict__ W, const float* __restrict__ MA,
    const float* __restrict__ REL, const float* __restrict__ NC,
    const int* __restrict__ cnt, const int* __restrict__ offs_h,
    const int* __restrict__ list_h,
    const int* __restrict__ cnt_l, const int* __restrict__ offs_l,
    const int* __restrict__ list_l, const int* __restrict__ slot_src,
    float* __restrict__ outW, float* __restrict__ outMA,
    float* __restrict__ outREL, float* __restrict__ outNC,
    float* __restrict__ outLoss, int K, int D, float invB)
{
    int k = (blockIdx.x * 256 + threadIdx.x) >> 6;    // wave id == node
    int ln = threadIdx.x & 63;
    if (k >= K) return;
    size_t ro = (size_t)k * D + ln * 8;               // 64 lanes x 8 = 512
    int src = slot_src[k];
    int n = cnt[k];

    if (src >= 0) {
        // created slot: mean of low-list of src node (created slots have cnt==0)
        int m = cnt_l[src];
        int base = offs_l[src];
        f32x4 s0 = {0.f,0.f,0.f,0.f}, s1 = {0.f,0.f,0.f,0.f};
        for (int i = 0; i < m; i++) {
            int b = list_l[base + i];
            const f32x4* xr = (const f32x4*)(X + (size_t)b * D + ln * 8);
            s0 += xr[0]; s1 += xr[1];
        }
        float fm = (float)m;
        f32x4 one = {1.f,1.f,1.f,1.f}, zero = {0.f,0.f,0.f,0.f};
#pragma unroll
        for (int j = 0; j < 4; j++) { s0[j] /= fm; s1[j] /= fm; }
        ((f32x4*)(outW + ro))[0] = s0;  ((f32x4*)(outW + ro))[1] = s1;
        ((f32x4*)(outMA + ro))[0] = zero; ((f32x4*)(outMA + ro))[1] = zero;
        ((f32x4*)(outREL + ro))[0] = one; ((f32x4*)(outREL + ro))[1] = one;
        if (ln == 0) outNC[k] = 1.f;
    } else if (n > 0) {
        int base = offs_h[k];
        f32x4 s0 = {0.f,0.f,0.f,0.f}, s1 = {0.f,0.f,0.f,0.f};
        for (int i = 0; i < n; i++) {
            int b = list_h[base + i];
            const f32x4* xr = (const f32x4*)(X + (size_t)b * D + ln * 8);
            s0 += xr[0]; s1 += xr[1];
        }
        float fn = (float)n;
        f32x4 wv0 = ((const f32x4*)(W + ro))[0],  wv1 = ((const f32x4*)(W + ro))[1];
        f32x4 av0 = ((const f32x4*)(MA + ro))[0], av1 = ((const f32x4*)(MA + ro))[1];
        float mean[8], w[8], m[8], d[8];
#pragma unroll
        for (int j = 0; j < 4; j++) {
            mean[j]     = s0[j] / fn;  mean[j + 4] = s1[j] / fn;
            w[j] = wv0[j]; w[j + 4] = wv1[j];
            m[j]     = AC * fabsf(mean[j] - w[j]) + OMAC * av0[j];
            m[j + 4] = AC * fabsf(mean[j + 4] - w[j + 4]) + OMAC * av1[j];
        }
        float vmax = m[0], vmin = m[0], vsum = 0.f;
#pragma unroll
        for (int j = 0; j < 8; j++) {
            vmax = fmaxf(vmax, m[j]); vmin = fminf(vmin, m[j]); vsum += m[j];
        }
#pragma unroll
        for (int o = 1; o < 64; o <<= 1) {
            vmax = fmaxf(vmax, __shfl_xor(vmax, o));
            vmin = fminf(vmin, __shfl_xor(vmin, o));
            vsum += __shfl_xor(vsum, o);
        }
        float av = vsum / (float)D;
        float iscale = 1.f / (EPSC * (vmax - vmin));
        f32x4 mo0, mo1, ro0, ro1, wo0, wo1;
        float ls = 0.f;
#pragma unroll
        for (int j = 0; j < 8; j++) {
            float r = 1.f / (1.f + expf((m[j] - av) * iscale));
            d[j] = LRC * (mean[j] - w[j]);
            ls += d[j];
            float wn = w[j] + d[j];
            if (j < 4) { mo0[j] = m[j]; ro0[j] = r; wo0[j] = wn; }
            else       { mo1[j-4] = m[j]; ro1[j-4] = r; wo1[j-4] = wn; }
        }
        ((f32x4*)(outW + ro))[0] = wo0;  ((f32x4*)(outW + ro))[1] = wo1;
        ((f32x4*)(outMA + ro))[0] = mo0; ((f32x4*)(outMA + ro))[1] = mo1;
        ((f32x4*)(outREL + ro))[0] = ro0; ((f32x4*)(outREL + ro))[1] = ro1;
#pragma unroll
        for (int o = 1; o < 64; o <<= 1) ls += __shfl_xor(ls, o);
        if (ln == 0) {
            atomicAdd(outLoss, ls * invB);
            outNC[k] = 1.f;
        }
    } else {
        f32x4 a0 = ((const f32x4*)(W + ro))[0],  a1 = ((const f32x4*)(W + ro))[1];
        f32x4 b0 = ((const f32x4*)(MA + ro))[0], b1 = ((const f32x4*)(MA + ro))[1];
        f32x4 c0 = ((const f32x4*)(REL + ro))[0], c1 = ((const f32x4*)(REL + ro))[1];
        ((f32x4*)(outW + ro))[0] = a0;  ((f32x4*)(outW + ro))[1] = a1;
        ((f32x4*)(outMA + ro))[0] = b0; ((f32x4*)(outMA + ro))[1] = b1;
        ((f32x4*)(outREL + ro))[0] = c0; ((f32x4*)(outREL + ro))[1] = c1;
        if (ln == 0) outNC[k] = NC[k];
    }
}

// ---------------- launch -----------------------------------------------------
extern "C" void kernel_launch(void* const* d_in, const int* in_sizes, int n_in,
                              void* d_out, int out_size, void* d_ws, size_t ws_size,
                              hipStream_t stream) {
    const float* X   = (const float*)d_in[0];
    const float* W   = (const float*)d_in[1];
    const float* MA  = (const float*)d_in[2];
    const float* REL = (const float*)d_in[3];
    const float* NC  = (const float*)d_in[4];

    const int K = in_sizes[4];              // 4096
    const int D = in_sizes[1] / K;          // 512
    const int B = in_sizes[0] / D;          // 8192
    const int NKT = K / BN;                 // 32
    const size_t KD = (size_t)K * D;
    const size_t BD = (size_t)B * D;

    float* out = (float*)d_out;
    float* outLoss = out;
    float* outW   = out + 1;
    float* outMA  = out + 1 + KD;
    float* outREL = out + 1 + 2 * KD;
    float* outNC  = out + 1 + 3 * KD;

    float* wsf = (float*)d_ws;
    size_t off = 0;
    ushort_t* Xh = (ushort_t*)(wsf + off); off += BD / 2;
    ushort_t* Wh = (ushort_t*)(wsf + off); off += KD / 2;
    float* rel_sum = wsf + off; off += K;
    float* wsq     = wsf + off; off += K;
    float* xsq     = wsf + off; off += B;
    float* tmaxA   = wsf + off; off += (size_t)B * NKT;
    int*   cntA    = (int*)(wsf + off); off += (size_t)B * NKT;
    float* actsA   = wsf + off; off += (size_t)B * NKT * 8;
    int*   idxsA   = (int*)(wsf + off); off += (size_t)B * NKT * 8;
    int*   idxb    = (int*)(wsf + off); off += B;
    int*   rankb   = (int*)(wsf + off); off += B;
    int*   highb   = (int*)(wsf + off); off += B;
    int*   list_h  = (int*)(wsf + off); off += B;
    int*   list_l  = (int*)(wsf + off); off += B;
    int*   offs_h  = (int*)(wsf + off); off += K;
    int*   offs_l  = (int*)(wsf + off); off += K;
    int*   slot_src = (int*)(wsf + off); off += K;
    int*   cnt     = (int*)(wsf + off); off += K;
    int*   cnt_l   = (int*)(wsf + off); off += K;

    k_prep<<<B + K, 128, 0, stream>>>(X, W, REL, Xh, Wh, xsq, wsq, rel_sum,
                                      cnt, cnt_l, outLoss, B, D);
    k_gemm_act<<<(B / BM) * (K / BN), 256, 0, stream>>>(Xh, Wh, xsq, wsq, rel_sum,
                                                        tmaxA, cntA, actsA, idxsA,
                                                        K, D);
    k_refine<<<B, 64, 0, stream>>>(X, W, xsq, wsq, rel_sum,
                                   tmaxA, cntA, actsA, idxsA, NKT,
                                   cnt, cnt_l, idxb, rankb, highb, K, D);
    k_offsets<<<1, 1024, 0, stream>>>(cnt, cnt_l, NC, offs_h, offs_l,
                                      slot_src, K);
    k_scatter<<<(B + 255) / 256, 256, 0, stream>>>(idxb, rankb, highb,
                                                   offs_h, offs_l,
                                                   list_h, list_l, B);
    k_final<<<K / 4, 256, 0, stream>>>(X, W, MA, REL, NC, cnt, offs_h, list_h,
                                       cnt_l, offs_l, list_l, slot_src,
                                       outW, outMA, outREL, outNC, outLoss,
                                       K, D, 1.f / (float)B);
}